// Round 1
// baseline (180.250 us; speedup 1.0000x reference)
//
#include <hip/hip_runtime.h>
#include <math.h>

#define N 4096
#define BSZ 2048
#define D 128
#define NDIST 199
#define PI_F 3.14159265358979323846f

// cf[i] = features[i % bsz, i / bsz, :]  (view-major stacking)
__device__ __forceinline__ int rowbase(int i) {
    return (i & (BSZ - 1)) * (2 * D) + (i >> 11) * D;
}

// ws layout (floats): m[0..N), S1[N..2N), sumc[2N..3N), cnt[3N..4N)
__global__ void init_kernel(const float* __restrict__ feat, float* __restrict__ ws) {
    int i = blockIdx.x * 256 + threadIdx.x;
    if (i >= N) return;
    const float* p = feat + rowbase(i);
    float dot = 0.f;
#pragma unroll
    for (int k = 0; k < D; k += 4) {
        float4 v = *(const float4*)(p + k);
        dot += v.x * v.x + v.y * v.y + v.z * v.z + v.w * v.w;
    }
    // rowmax of clipped cos_theta = clipped diagonal (all off-diag cosines < 1)
    ws[i] = fminf(fmaxf(dot, -1.f), 1.f);
    ws[N + i] = 0.f;
    ws[2 * N + i] = 0.f;
    ws[3 * N + i] = 0.f;
}

__launch_bounds__(256)
__global__ void pair_kernel(const float* __restrict__ feat, const int* __restrict__ labels,
                            float* __restrict__ ws) {
    __shared__ __align__(16) float AI[64 * 128];   // 64 rows x full K, swizzled
    __shared__ __align__(16) float AJ[128 * 32];   // 128 cols x K-quarter, swizzled
    __shared__ float cosT[NDIST], sinT[NDIST];

    const int t = threadIdx.x;
    const int bi = blockIdx.x >> 5;   // 0..63  -> i0 = bi*64
    const int bj = blockIdx.x & 31;   // 0..31  -> j0 = bj*128
    const int i0 = bi * 64, j0 = bj * 128;

    // phi tables: dist in [-99,99] -> idx = dist+99
    if (t < NDIST) {
        float dist = (float)(t - 99);
        float phi = (1.0f - dist / 100.0f) * PI_F;
        cosT[t] = cosf(phi);
        sinT[t] = fabsf(sinf(phi));
    }

    // stage AI: 64 rows x 128 floats, XOR-swizzled on 4-dword groups
#pragma unroll
    for (int s = 0; s < 8; ++s) {
        int idx = t + 256 * s;
        int row = idx >> 5, kq = idx & 31;
        float4 v = *(const float4*)(feat + rowbase(i0 + row) + kq * 4);
        *(float4*)&AI[row * 128 + ((kq * 4) ^ ((row & 7) << 2))] = v;
    }

    const int tx = t & 15, ty = t >> 4;
    const int sI = (ty & 7) << 2;
    const int sJ = (tx & 7) << 2;

    float acc[4][8];
#pragma unroll
    for (int r = 0; r < 4; ++r)
#pragma unroll
        for (int c = 0; c < 8; ++c) acc[r][c] = 0.f;

    for (int q = 0; q < 4; ++q) {
        __syncthreads();
        // stage AJ: 128 rows x 32 floats (k in [q*32, q*32+32))
#pragma unroll
        for (int s = 0; s < 4; ++s) {
            int idx = t + 256 * s;
            int row = idx >> 3, kqi = idx & 7;
            float4 v = *(const float4*)(feat + rowbase(j0 + row) + q * 32 + kqi * 4);
            *(float4*)&AJ[row * 32 + ((kqi * 4) ^ ((row & 7) << 2))] = v;
        }
        __syncthreads();
#pragma unroll
        for (int kq = 0; kq < 8; ++kq) {
            int k2 = q * 8 + kq;
            float4 ai[4], aj[8];
#pragma unroll
            for (int r = 0; r < 4; ++r)
                ai[r] = *(const float4*)&AI[(ty + 16 * r) * 128 + ((k2 * 4) ^ sI)];
#pragma unroll
            for (int c = 0; c < 8; ++c)
                aj[c] = *(const float4*)&AJ[(tx + 16 * c) * 32 + ((kq * 4) ^ sJ)];
#pragma unroll
            for (int r = 0; r < 4; ++r)
#pragma unroll
                for (int c = 0; c < 8; ++c)
                    acc[r][c] += ai[r].x * aj[c].x + ai[r].y * aj[c].y
                               + ai[r].z * aj[c].z + ai[r].w * aj[c].w;
        }
    }

    // epilogue
    int labI[4], labJ[8];
    float mI[4];
#pragma unroll
    for (int r = 0; r < 4; ++r) {
        int gi = i0 + ty + 16 * r;
        labI[r] = labels[gi & (BSZ - 1)];
        mI[r] = ws[gi];
    }
#pragma unroll
    for (int c = 0; c < 8; ++c) {
        int gj = j0 + tx + 16 * c;
        labJ[c] = labels[gj & (BSZ - 1)];
    }

#pragma unroll
    for (int r = 0; r < 4; ++r) {
        int gi = i0 + ty + 16 * r;
        float s1 = 0.f, sc = 0.f, ct = 0.f;
#pragma unroll
        for (int c = 0; c < 8; ++c) {
            int gj = j0 + tx + 16 * c;
            if (gi == gj) continue;   // diagonal excluded from all sums
            float cth = fminf(fmaxf(acc[r][c], -1.f), 1.f);
            int dist = labI[r] - labJ[c];
            if (dist == 0) {
                // masked positive: exp(logits) = exp(c - rowmax)
                s1 += __expf(cth - mI[r]);
                sc += cth;
                ct += 1.f;
            } else {
                int idx = dist + 99;
                float st = sqrtf(1.f - cth * cth + 1e-6f);
                float nl = cth * cosT[idx] - st * sinT[idx];
                s1 += __expf(nl);
            }
        }
        // reduce across the 16 tx lanes that share row gi (same wave)
#pragma unroll
        for (int off = 1; off < 16; off <<= 1) {
            s1 += __shfl_xor(s1, off);
            sc += __shfl_xor(sc, off);
            ct += __shfl_xor(ct, off);
        }
        if (tx == 0) {
            atomicAdd(&ws[N + gi], s1);
            atomicAdd(&ws[2 * N + gi], sc);
            atomicAdd(&ws[3 * N + gi], ct);
        }
    }
}

__global__ void final_kernel(const float* __restrict__ ws, float* __restrict__ out) {
    __shared__ float red[256];
    int t = threadIdx.x;
    float sum = 0.f;
    for (int i = t; i < N; i += 256) {
        float ct = ws[3 * N + i];
        float lp = ws[2 * N + i] - ct * ws[i] - ct * logf(ws[N + i]);
        sum += (lp + 1e-6f) / (ct + 1e-6f);
    }
    red[t] = sum;
    __syncthreads();
    for (int s = 128; s > 0; s >>= 1) {
        if (t < s) red[t] += red[t + s];
        __syncthreads();
    }
    if (t == 0) out[0] = -red[0] / (float)N;
}

extern "C" void kernel_launch(void* const* d_in, const int* in_sizes, int n_in,
                              void* d_out, int out_size, void* d_ws, size_t ws_size,
                              hipStream_t stream) {
    const float* feat = (const float*)d_in[0];
    const int* labels = (const int*)d_in[1];
    float* ws = (float*)d_ws;
    float* out = (float*)d_out;

    init_kernel<<<16, 256, 0, stream>>>(feat, ws);
    pair_kernel<<<2048, 256, 0, stream>>>(feat, labels, ws);
    final_kernel<<<1, 256, 0, stream>>>(ws, out);
}

// Round 2
// 59.651 us; speedup vs baseline: 3.0217x; 3.0217x over previous
//
#include <hip/hip_runtime.h>
#include <math.h>

#define N 4096
#define BSZ 2048
#define D 128
#define NDIST 199
#define PI_F 3.14159265358979323846f

typedef __bf16 bf16x8 __attribute__((ext_vector_type(8)));
typedef float f32x4 __attribute__((ext_vector_type(4)));
typedef unsigned short u16x8 __attribute__((ext_vector_type(8)));

// cf[i] = features[i % bsz, i / bsz, :]  (view-major stacking)
__device__ __forceinline__ int rowbase(int i) {
    return (i & (BSZ - 1)) * (2 * D) + (i >> 11) * D;
}

__device__ __forceinline__ unsigned short f2bf(float x) {
    unsigned u = __float_as_uint(x);
    return (unsigned short)((u + 0x7fffu + ((u >> 16) & 1u)) >> 16);  // RNE
}

// ws layout: floats m[0..N) S1[N..2N) sumc[2N..3N) cnt[3N..4N); then bf16 cf[N][D]
__global__ void init_kernel(const float* __restrict__ feat, float* __restrict__ ws,
                            unsigned short* __restrict__ cf) {
    int t = threadIdx.x;
    int row = blockIdx.x * 16 + (t >> 4);   // 16 rows per 256-thread block
    int lq = t & 15;                        // 16 lanes per row, 8 floats each
    const float* p = feat + rowbase(row) + lq * 8;
    float4 v0 = *(const float4*)(p);
    float4 v1 = *(const float4*)(p + 4);
    float dot = v0.x * v0.x + v0.y * v0.y + v0.z * v0.z + v0.w * v0.w
              + v1.x * v1.x + v1.y * v1.y + v1.z * v1.z + v1.w * v1.w;
#pragma unroll
    for (int off = 1; off < 16; off <<= 1) dot += __shfl_xor(dot, off);

    u16x8 u;
    u[0] = f2bf(v0.x); u[1] = f2bf(v0.y); u[2] = f2bf(v0.z); u[3] = f2bf(v0.w);
    u[4] = f2bf(v1.x); u[5] = f2bf(v1.y); u[6] = f2bf(v1.z); u[7] = f2bf(v1.w);
    *(u16x8*)(cf + row * D + lq * 8) = u;

    if (lq == 0) {
        ws[row] = fminf(fmaxf(dot, -1.f), 1.f);  // rowmax = clipped diagonal
        ws[N + row] = 0.f;
        ws[2 * N + row] = 0.f;
        ws[3 * N + row] = 0.f;
    }
}

__launch_bounds__(256)
__global__ void pair_kernel(const unsigned short* __restrict__ cf,
                            const int* __restrict__ labels, float* __restrict__ ws) {
    __shared__ float cosT[NDIST], sinT[NDIST];
    __shared__ int labI[128], labJ[128];
    __shared__ float mI[128];

    const int t = threadIdx.x;
    const int bi = blockIdx.x >> 5;   // 32x32 grid of 128x128 tiles
    const int bj = blockIdx.x & 31;
    const int i0 = bi * 128, j0 = bj * 128;

    if (t < NDIST) {
        float phi = (1.0f - (float)(t - 99) / 100.0f) * PI_F;
        cosT[t] = cosf(phi);
        sinT[t] = fabsf(sinf(phi));
    }
    if (t < 128) {
        labI[t] = labels[(i0 + t) & (BSZ - 1)];
        mI[t] = ws[i0 + t];
    } else {
        int u = t - 128;
        labJ[u] = labels[(j0 + u) & (BSZ - 1)];
    }
    __syncthreads();

    const int wid = t >> 6, lane = t & 63;
    const int wr = wid >> 1, wc = wid & 1;          // wave -> 64x64 quadrant
    const int lrow = lane & 15, lk = (lane >> 4) * 8;

    // fragment bases: A from I-rows, B from J-rows (Gram: B^T layout == row-major cf)
    const unsigned short* A0 = cf + (size_t)(i0 + wr * 64 + lrow) * D + lk;
    const unsigned short* B0 = cf + (size_t)(j0 + wc * 64 + lrow) * D + lk;

    f32x4 acc[4][4] = {};
#pragma unroll
    for (int ks = 0; ks < 4; ++ks) {
        bf16x8 a[4], b[4];
#pragma unroll
        for (int r = 0; r < 4; ++r) a[r] = *(const bf16x8*)(A0 + r * 16 * D + ks * 32);
#pragma unroll
        for (int c = 0; c < 4; ++c) b[c] = *(const bf16x8*)(B0 + c * 16 * D + ks * 32);
#pragma unroll
        for (int r = 0; r < 4; ++r)
#pragma unroll
            for (int c = 0; c < 4; ++c)
                acc[r][c] = __builtin_amdgcn_mfma_f32_16x16x32_bf16(a[r], b[c], acc[r][c], 0, 0, 0);
    }

    // epilogue: C/D layout col=lane&15, row=(lane>>4)*4+reg  [m89-verified]
#pragma unroll
    for (int ar = 0; ar < 4; ++ar) {
#pragma unroll
        for (int rg = 0; rg < 4; ++rg) {
            int ri = wr * 64 + ar * 16 + ((lane >> 4) << 2) + rg;  // row in tile
            int gi = i0 + ri;
            int li = labI[ri];
            float m = mI[ri];
            float s1 = 0.f, sc = 0.f, ct = 0.f;
#pragma unroll
            for (int ac = 0; ac < 4; ++ac) {
                int cj = wc * 64 + ac * 16 + (lane & 15);
                int gj = j0 + cj;
                float cth = fminf(fmaxf(acc[ar][ac][rg], -1.f), 1.f);
                if (gi != gj) {
                    int dist = li - labJ[cj];
                    if (dist == 0) {
                        s1 += __expf(cth - m);   // positive: exp(logits)
                        sc += cth;
                        ct += 1.f;
                    } else {
                        int idx = dist + 99;
                        float st = sqrtf(1.f - cth * cth + 1e-6f);
                        s1 += __expf(cth * cosT[idx] - st * sinT[idx]);
                    }
                }
            }
#pragma unroll
            for (int off = 1; off < 16; off <<= 1) {
                s1 += __shfl_xor(s1, off);
                sc += __shfl_xor(sc, off);
                ct += __shfl_xor(ct, off);
            }
            if ((lane & 15) == 0) {
                atomicAdd(&ws[N + gi], s1);
                atomicAdd(&ws[2 * N + gi], sc);
                atomicAdd(&ws[3 * N + gi], ct);
            }
        }
    }
}

__global__ void final_kernel(const float* __restrict__ ws, float* __restrict__ out) {
    __shared__ float red[256];
    int t = threadIdx.x;
    float sum = 0.f;
    for (int i = t; i < N; i += 256) {
        float ct = ws[3 * N + i];
        float lp = ws[2 * N + i] - ct * ws[i] - ct * logf(ws[N + i]);
        sum += (lp + 1e-6f) / (ct + 1e-6f);
    }
    red[t] = sum;
    __syncthreads();
    for (int s = 128; s > 0; s >>= 1) {
        if (t < s) red[t] += red[t + s];
        __syncthreads();
    }
    if (t == 0) out[0] = -red[0] / (float)N;
}

extern "C" void kernel_launch(void* const* d_in, const int* in_sizes, int n_in,
                              void* d_out, int out_size, void* d_ws, size_t ws_size,
                              hipStream_t stream) {
    const float* feat = (const float*)d_in[0];
    const int* labels = (const int*)d_in[1];
    float* ws = (float*)d_ws;
    unsigned short* cf = (unsigned short*)((float*)d_ws + 4 * N);
    float* out = (float*)d_out;

    init_kernel<<<N / 16, 256, 0, stream>>>(feat, ws, cf);
    pair_kernel<<<1024, 256, 0, stream>>>(cf, labels, ws);
    final_kernel<<<1, 256, 0, stream>>>(ws, out);
}

// Round 3
// 39.836 us; speedup vs baseline: 4.5248x; 1.4974x over previous
//
#include <hip/hip_runtime.h>
#include <math.h>

#define N 4096
#define BSZ 2048
#define D 128
#define NDIST 199
#define PI_F 3.14159265358979323846f

typedef __bf16 bf16x8 __attribute__((ext_vector_type(8)));
typedef float f32x4 __attribute__((ext_vector_type(4)));
typedef unsigned short u16x8 __attribute__((ext_vector_type(8)));

// cf[i] = features[i % bsz, i / bsz, :]  (view-major stacking)
__device__ __forceinline__ int rowbase(int i) {
    return (i & (BSZ - 1)) * (2 * D) + (i >> 11) * D;
}

__device__ __forceinline__ unsigned short f2bf(float x) {
    unsigned u = __float_as_uint(x);
    return (unsigned short)((u + 0x7fffu + ((u >> 16) & 1u)) >> 16);  // RNE
}

// ws layout: floats m[0..N) S1[N..2N) sumc[2N..3N) cnt[3N..4N); then bf16 cf[N][D]
__global__ void init_kernel(const float* __restrict__ feat, float* __restrict__ ws,
                            unsigned short* __restrict__ cf) {
    int t = threadIdx.x;
    int row = blockIdx.x * 16 + (t >> 4);   // 16 rows per 256-thread block
    int lq = t & 15;                        // 16 lanes per row, 8 floats each
    const float* p = feat + rowbase(row) + lq * 8;
    float4 v0 = *(const float4*)(p);
    float4 v1 = *(const float4*)(p + 4);
    float dot = v0.x * v0.x + v0.y * v0.y + v0.z * v0.z + v0.w * v0.w
              + v1.x * v1.x + v1.y * v1.y + v1.z * v1.z + v1.w * v1.w;
#pragma unroll
    for (int off = 1; off < 16; off <<= 1) dot += __shfl_xor(dot, off);

    u16x8 u;
    u[0] = f2bf(v0.x); u[1] = f2bf(v0.y); u[2] = f2bf(v0.z); u[3] = f2bf(v0.w);
    u[4] = f2bf(v1.x); u[5] = f2bf(v1.y); u[6] = f2bf(v1.z); u[7] = f2bf(v1.w);
    *(u16x8*)(cf + row * D + lq * 8) = u;

    if (lq == 0) {
        ws[row] = fminf(fmaxf(dot, -1.f), 1.f);  // rowmax = clipped diagonal
        ws[N + row] = 0.f;
        ws[2 * N + row] = 0.f;
        ws[3 * N + row] = 0.f;
    }
}

__launch_bounds__(256)
__global__ void pair_kernel(const unsigned short* __restrict__ cf,
                            const int* __restrict__ labels, float* __restrict__ ws) {
    __shared__ float2 tab[NDIST];
    __shared__ int labI[128], labJ[128];
    __shared__ float mI[128];

    const int t = threadIdx.x;
    const int bi = blockIdx.x >> 5;   // 32x32 grid of 128x128 tiles
    const int bj = blockIdx.x & 31;
    const int i0 = bi * 128, j0 = bj * 128;

    if (t < NDIST) {
        float phi = (1.0f - (float)(t - 99) / 100.0f) * PI_F;
        tab[t] = make_float2(cosf(phi), fabsf(sinf(phi)));
    }
    if (t < 128) {
        labI[t] = labels[(i0 + t) & (BSZ - 1)];
        mI[t] = ws[i0 + t];
    } else {
        int u = t - 128;
        labJ[u] = labels[(j0 + u) & (BSZ - 1)];
    }
    __syncthreads();

    const int wid = t >> 6, lane = t & 63;
    const int wp = wid >> 1, wc_ = wid & 1;     // wp: I half, wc_: J half
    const int lrow = lane & 15, lk = (lane >> 4) * 8;

    // SWAPPED operands: A = J rows, B = I rows -> D[row=J][col=I]
    const unsigned short* A0 = cf + (size_t)(j0 + wc_ * 64 + lrow) * D + lk;
    const unsigned short* B0 = cf + (size_t)(i0 + wp * 64 + lrow) * D + lk;

    f32x4 acc[4][4] = {};   // [ar: J fragment][ac: I fragment]
#pragma unroll
    for (int ks = 0; ks < 4; ++ks) {
        bf16x8 a[4], b[4];
#pragma unroll
        for (int r = 0; r < 4; ++r) a[r] = *(const bf16x8*)(A0 + r * 16 * D + ks * 32);
#pragma unroll
        for (int c = 0; c < 4; ++c) b[c] = *(const bf16x8*)(B0 + c * 16 * D + ks * 32);
#pragma unroll
        for (int r = 0; r < 4; ++r)
#pragma unroll
            for (int c = 0; c < 4; ++c)
                acc[r][c] = __builtin_amdgcn_mfma_f32_16x16x32_bf16(a[r], b[c], acc[r][c], 0, 0, 0);
    }

    // per-lane J labels: jr_local = wc_*64 + ar*16 + (lane>>4)*4 + rg  (ac-independent)
    const int jb = wc_ * 64 + ((lane >> 4) << 2);
    int lj[16];
#pragma unroll
    for (int ar = 0; ar < 4; ++ar)
#pragma unroll
        for (int rg = 0; rg < 4; ++rg)
            lj[ar * 4 + rg] = labJ[jb + ar * 16 + rg];

    const bool hasDiag = (bi == bj);

#pragma unroll
    for (int ac = 0; ac < 4; ++ac) {
        const int ri = wp * 64 + ac * 16 + (lane & 15);   // I index (lane-local row)
        const int gi = i0 + ri;
        const int li = labI[ri];
        const float m = mI[ri];
        float s1 = 0.f, sc = 0.f, ct = 0.f;
#pragma unroll
        for (int ar = 0; ar < 4; ++ar) {
#pragma unroll
            for (int rg = 0; rg < 4; ++rg) {
                float c = fminf(fmaxf(acc[ar][ac][rg], -1.f), 1.f);
                int dist = li - lj[ar * 4 + rg];
                float2 cs = tab[dist + 99];
                float st = __builtin_amdgcn_sqrtf(fmaf(-c, c, 1.000001f));
                float nl = fmaf(c, cs.x, -st * cs.y);
                bool pos = (dist == 0);
                float logit = pos ? (c - m) : nl;
                bool diag = hasDiag && (ri == jb + ar * 16 + rg);
                float e = diag ? 0.f : __expf(logit);
                s1 += e;
                bool p = pos && !diag;
                sc += p ? c : 0.f;
                ct += p ? 1.f : 0.f;
            }
        }
        // combine the 4 lane-groups (same gi at lane&15): xor 16, then 32
        s1 += __shfl_xor(s1, 16); s1 += __shfl_xor(s1, 32);
        sc += __shfl_xor(sc, 16); sc += __shfl_xor(sc, 32);
        ct += __shfl_xor(ct, 16); ct += __shfl_xor(ct, 32);
        if (lane < 16) {
            atomicAdd(&ws[N + gi], s1);
            atomicAdd(&ws[2 * N + gi], sc);
            atomicAdd(&ws[3 * N + gi], ct);
        }
    }
}

__global__ void final_kernel(const float* __restrict__ ws, float* __restrict__ out) {
    __shared__ float red[256];
    int t = threadIdx.x;
    float sum = 0.f;
    for (int i = t; i < N; i += 256) {
        float ct = ws[3 * N + i];
        float lp = ws[2 * N + i] - ct * ws[i] - ct * __logf(ws[N + i]);
        sum += (lp + 1e-6f) / (ct + 1e-6f);
    }
    red[t] = sum;
    __syncthreads();
    for (int s = 128; s > 0; s >>= 1) {
        if (t < s) red[t] += red[t + s];
        __syncthreads();
    }
    if (t == 0) out[0] = -red[0] / (float)N;
}

extern "C" void kernel_launch(void* const* d_in, const int* in_sizes, int n_in,
                              void* d_out, int out_size, void* d_ws, size_t ws_size,
                              hipStream_t stream) {
    const float* feat = (const float*)d_in[0];
    const int* labels = (const int*)d_in[1];
    float* ws = (float*)d_ws;
    unsigned short* cf = (unsigned short*)((float*)d_ws + 4 * N);
    float* out = (float*)d_out;

    init_kernel<<<N / 16, 256, 0, stream>>>(feat, ws, cf);
    pair_kernel<<<1024, 256, 0, stream>>>(cf, labels, ws);
    final_kernel<<<1, 256, 0, stream>>>(ws, out);
}